// Round 6
// baseline (169.528 us; speedup 1.0000x reference)
//
#include <hip/hip_runtime.h>
#include <hip/hip_bf16.h>

// Problem constants (from reference)
#define B_    8
#define C_    128
#define H_    64
#define W_    64
#define COUT_ 128
#define K_    3
#define K2_   9
#define JOFF_ 18            // 2*K*K offset channels
#define HW_   (H_*W_)       // 4096
#define CK_   (C_*K2_)      // 1152

typedef short  short8 __attribute__((ext_vector_type(8)));   // 8 bf16 in 4 VGPR
typedef float  f32x4  __attribute__((ext_vector_type(4)));

__device__ __forceinline__ ushort f2bf(float f) {
    __hip_bfloat16 h = __float2bfloat16(f);
    return *reinterpret_cast<ushort*>(&h);
}

// ---------------------------------------------------------------------------
// Kernel A: offset conv (3x3, pad 1, stride 1) + bias.
// Block = one (b,row), 512 threads: 8 waves = 8 channel-eighths (16 ch each),
// each thread keeps all 18 output-channel accumulators in VGPRs.
// ---------------------------------------------------------------------------
__global__ __launch_bounds__(512) void offset_conv_kernel(
    const float* __restrict__ x, const float* __restrict__ w_off,
    const float* __restrict__ b_off, float* __restrict__ offs)
{
    __shared__ float red[7][JOFF_][64];      // 32.3 KB partials from waves 1..7

    const int bid  = blockIdx.x;             // 512 blocks
    const int nbid = ((bid & 7) << 6) + (bid >> 3);   // XCD chunking: 1 image/XCD
    const int b    = nbid >> 6;
    const int row  = nbid & 63;

    const int t  = threadIdx.x;
    const int s  = t & 63;                   // position in row
    const int wv = t >> 6;                   // channel eighth 0..7
    const int wvu = __builtin_amdgcn_readfirstlane(wv);

    float m[K2_]; int idx[K2_];
#pragma unroll
    for (int ky = 0; ky < 3; ++ky) {
#pragma unroll
        for (int kx = 0; kx < 3; ++kx) {
            int y  = row - 1 + ky;
            int xx = s  - 1 + kx;
            bool v = (y >= 0) & (y < H_) & (xx >= 0) & (xx < W_);
            int yc = min(max(y, 0), H_ - 1);
            int xc = min(max(xx, 0), W_ - 1);
            m[ky*3+kx]   = v ? 1.0f : 0.0f;
            idx[ky*3+kx] = yc * W_ + xc;
        }
    }

    const float* xb = x + ((size_t)b << 19) + ((size_t)wvu << 16);  // 16 ch
    const float* wb = w_off + wvu * 16 * K2_;

    float acc[JOFF_];
#pragma unroll
    for (int j = 0; j < JOFF_; ++j) acc[j] = 0.f;

    for (int c = 0; c < 16; ++c) {
        const float* xc = xb + (c << 12);
        float xv[K2_];
#pragma unroll
        for (int k = 0; k < K2_; ++k) xv[k] = xc[idx[k]] * m[k];
#pragma unroll
        for (int k = 0; k < K2_; ++k) {
            const float* wp = wb + c * K2_ + k;
#pragma unroll
            for (int j = 0; j < JOFF_; ++j)
                acc[j] = fmaf(wp[(size_t)j * CK_], xv[k], acc[j]);
        }
    }

    if (wv > 0) {
#pragma unroll
        for (int j = 0; j < JOFF_; ++j) red[wv-1][j][s] = acc[j];
    }
    __syncthreads();
    if (wv == 0) {
        float r;
#pragma unroll
        for (int j = 0; j < JOFF_; ++j) {
            r = acc[j];
#pragma unroll
            for (int w = 0; w < 7; ++w) r += red[w][j][s];
            r += b_off[j];
            offs[((size_t)(b * JOFF_ + j) << 12) + (row << 6) + s] = r;
        }
    }
}

// ---------------------------------------------------------------------------
// Kernel T: w_def -> wt[k][o][c] bf16 (tap-major, LINEAR — A is read straight
// from L1/L2 by the GEMM waves, coalesced b128 per 16-row fragment).
// ---------------------------------------------------------------------------
__global__ __launch_bounds__(256) void transpose_wdef_kernel(
    const float* __restrict__ w_def, ushort* __restrict__ wt)
{
    int t = blockIdx.x * 256 + threadIdx.x;
    if (t >= K2_ * COUT_ * C_) return;
    int c = t & 127;
    int o = (t >> 7) & 127;
    int k = t >> 14;
    float v = w_def[((size_t)o * C_ + c) * K2_ + k];
    wt[((size_t)k * COUT_ + o) * C_ + c] = f2bf(v);
}

// ---------------------------------------------------------------------------
// Kernel B: fused deformable gather + MFMA GEMM, single barrier per tap.
// Block = 512 threads (8 waves, 2M x 4N), tile = 128 out-ch x 64 positions.
// Loop body: gather(k+1)->regs | MFMA(k) (A per-kc from L2, B from sB[k&1])
//            | ds_write(k+1)->sB[(k+1)&1] | barrier.
// ---------------------------------------------------------------------------
__global__ __launch_bounds__(512, 4) void deform_mfma_kernel(
    const float* __restrict__ x, const float* __restrict__ offs,
    const ushort* __restrict__ wt, float* __restrict__ out)
{
    __shared__ ushort sB[2][64][C_];         // 2 x 16 KB, XOR-swizzled
    __shared__ float  s_off[JOFF_][64];      // 4.6 KB raw offsets for this row

    const int bid  = blockIdx.x;             // 512 blocks
    const int nbid = ((bid & 7) << 6) + (bid >> 3);   // XCD chunking: 1 image/XCD
    const int s0   = nbid << 6;
    const int b    = s0 >> 12;
    const int hw0  = s0 & (HW_ - 1);
    const int ho   = hw0 >> 6;

    const int t    = threadIdx.x;
    const int wid  = t >> 6, lane = t & 63;
    const int wm   = wid >> 2, wn = wid & 3; // 2x4 wave grid: 64(M) x 16(N)
    const int sg   = lane;                   // gather position = lane
    const float* xb = x + ((size_t)b << 19);

    // Phase 0: cache this row's 18 offset planes in LDS (coalesced)
    for (int e = t; e < JOFF_ * 64; e += 512) {
        int j = e >> 6, s = e & 63;
        s_off[j][s] = offs[((size_t)(b * JOFF_ + j) << 12) + hw0 + s];
    }
    __syncthreads();

    const int swz  = (sg & 7) << 3;
    const int arow = lane & 15;
    const int akk  = (lane >> 4) << 3;

    f32x4 acc[4] = {};
    uint2 pk[4];

    // ---- gather one tap into pk[] registers (16 channels per thread)
    auto gather = [&](int k) {
        float dy = s_off[2*k    ][sg];
        float dx = s_off[2*k + 1][sg];
        float py = (float)(ho - 1 + k/3) + dy;
        float px = (float)(sg - 1 + k%3) + dx;
        float y0f = floorf(py), x0f = floorf(px);
        float wy = py - y0f,    wx = px - x0f;
        int y0 = (int)y0f, x0 = (int)x0f;
        int y1 = y0 + 1,   x1 = x0 + 1;
        float vy0 = (y0 >= 0 && y0 < H_) ? 1.f : 0.f;
        float vy1 = (y1 >= 0 && y1 < H_) ? 1.f : 0.f;
        float vx0 = (x0 >= 0 && x0 < W_) ? 1.f : 0.f;
        float vx1 = (x1 >= 0 && x1 < W_) ? 1.f : 0.f;
        int y0c = min(max(y0, 0), H_-1), y1c = min(max(y1, 0), H_-1);
        int x0c = min(max(x0, 0), W_-1), x1c = min(max(x1, 0), W_-1);
        int bx  = min(max(x0, 0), W_-2);     // column-pair base [bx, bx+1]
        // fold per-corner weights into coefficients on (p.x, p.y) of each row
        float wx0 = (1.f - wx) * vx0, wx1 = wx * vx1;
        float ex0 = (x0c == bx ? wx0 : 0.f) + (x1c == bx ? wx1 : 0.f);
        float ex1 = (x0c == bx ? 0.f : wx0) + (x1c == bx ? 0.f : wx1);
        float r0 = (1.f - wy) * vy0, r1 = wy * vy1;
        float a00 = r0*ex0, a01 = r0*ex1, a10 = r1*ex0, a11 = r1*ex1;
        const float* p0 = xb + ((size_t)wid << 16) + y0c*W_ + bx;  // +16ch base
        const float* p1 = xb + ((size_t)wid << 16) + y1c*W_ + bx;
#pragma unroll
        for (int j = 0; j < 4; ++j) {
            float v[4];
#pragma unroll
            for (int q = 0; q < 4; ++q) {
                const float* q0 = p0 + ((j*4 + q) << 12);
                const float* q1 = p1 + ((j*4 + q) << 12);
                float vv =      a00 * q0[0];
                vv = fmaf(a01, q0[1], vv);
                vv = fmaf(a10, q1[0], vv);
                vv = fmaf(a11, q1[1], vv);
                v[q] = vv;
            }
            pk[j].x = (uint)f2bf(v[0]) | ((uint)f2bf(v[1]) << 16);
            pk[j].y = (uint)f2bf(v[2]) | ((uint)f2bf(v[3]) << 16);
        }
    };

    auto store_pk = [&](int buf) {
#pragma unroll
        for (int j = 0; j < 4; ++j) {
            int c0 = wid*16 + j*4;
            *reinterpret_cast<uint2*>(&sB[buf][sg][c0 ^ swz]) = pk[j];
        }
    };

    // ---- prologue: tap 0 into sB[0]
    gather(0);
    store_pk(0);
    __syncthreads();

    for (int k = 0; k < K2_; ++k) {
        if (k < K2_ - 1) gather(k + 1);

        // MFMA(k): A per-kc from L2 (rolling prefetch), B from sB[k&1]
        {
            const ushort* wk = wt + (size_t)k * (COUT_ * C_);
            const int buf = k & 1;
            short8 aC[4], aN[4];
#pragma unroll
            for (int mi = 0; mi < 4; ++mi)
                aC[mi] = *reinterpret_cast<const short8*>(
                    wk + (wm*64 + mi*16 + arow) * C_ + akk);
#pragma unroll
            for (int kc = 0; kc < 4; ++kc) {
                if (kc < 3) {
#pragma unroll
                    for (int mi = 0; mi < 4; ++mi)
                        aN[mi] = *reinterpret_cast<const short8*>(
                            wk + (wm*64 + mi*16 + arow) * C_ + (kc+1)*32 + akk);
                }
                int srow = wn*16 + arow;
                short8 bF = *reinterpret_cast<const short8*>(
                    &sB[buf][srow][(kc*32 + akk) ^ ((srow & 7) << 3)]);
#pragma unroll
                for (int mi = 0; mi < 4; ++mi)
                    acc[mi] = __builtin_amdgcn_mfma_f32_16x16x32_bf16(
                        aC[mi], bF, acc[mi], 0, 0, 0);
#pragma unroll
                for (int mi = 0; mi < 4; ++mi) aC[mi] = aN[mi];
            }
        }

        if (k < K2_ - 1) store_pk((k + 1) & 1);
        __syncthreads();
    }

    // ---- epilogue: C/D layout col=lane&15, row=(lane>>4)*4+reg; nt stores
#pragma unroll
    for (int mi = 0; mi < 4; ++mi) {
#pragma unroll
        for (int r = 0; r < 4; ++r) {
            int o = wm*64 + mi*16 + ((lane >> 4) * 4 + r);
            int s = wn*16 + (lane & 15);
            __builtin_nontemporal_store(acc[mi][r],
                &out[(((size_t)(b*COUT_ + o)) << 12) + hw0 + s]);
        }
    }
}

// ---------------------------------------------------------------------------
extern "C" void kernel_launch(void* const* d_in, const int* in_sizes, int n_in,
                              void* d_out, int out_size, void* d_ws, size_t ws_size,
                              hipStream_t stream) {
    const float* x     = (const float*)d_in[0];
    const float* w_off = (const float*)d_in[1];
    const float* b_off = (const float*)d_in[2];
    const float* w_def = (const float*)d_in[3];
    float* out  = (float*)d_out;

    float*  offs = (float*)d_ws;                                    // 2,359,296 B
    ushort* wt   = (ushort*)((char*)d_ws + (size_t)B_*JOFF_*HW_*4); //   294,912 B

    // Kernel A: offsets (one block per (b,row))
    {
        offset_conv_kernel<<<B_ * H_, 512, 0, stream>>>(x, w_off, b_off, offs);
    }
    // Kernel T: w_def -> bf16 tap-major (linear)
    {
        int total  = K2_ * COUT_ * C_;
        int blocks = (total + 255) / 256;
        transpose_wdef_kernel<<<blocks, 256, 0, stream>>>(w_def, wt);
    }
    // Kernel B: fused gather + MFMA GEMM
    {
        int blocks = (B_ * HW_) / 64;   // 512
        deform_mfma_kernel<<<blocks, 512, 0, stream>>>(x, offs, wt, out);
    }
}

// Round 7
// 102.513 us; speedup vs baseline: 1.6537x; 1.6537x over previous
//
#include <hip/hip_runtime.h>
#include <hip/hip_bf16.h>

// Problem constants (from reference)
#define B_    8
#define C_    128
#define H_    64
#define W_    64
#define COUT_ 128
#define K_    3
#define K2_   9
#define JOFF_ 18            // 2*K*K offset channels
#define HW_   (H_*W_)       // 4096
#define CK_   (C_*K2_)      // 1152

typedef short  short8 __attribute__((ext_vector_type(8)));   // 8 bf16 in 4 VGPR
typedef float  f32x4  __attribute__((ext_vector_type(4)));

__device__ __forceinline__ ushort f2bf(float f) {
    __hip_bfloat16 h = __float2bfloat16(f);
    return *reinterpret_cast<ushort*>(&h);
}
__device__ __forceinline__ float bf2f(ushort u) {
    return __uint_as_float(((uint)u) << 16);
}

// ---------------------------------------------------------------------------
// Kernel A: offset conv (3x3, pad 1, stride 1) + bias.  (f32 x, NCHW — exact)
// Block = one (b,row), 512 threads = 8 channel-eighths; 18 accs in VGPRs.
// ---------------------------------------------------------------------------
__global__ __launch_bounds__(512) void offset_conv_kernel(
    const float* __restrict__ x, const float* __restrict__ w_off,
    const float* __restrict__ b_off, float* __restrict__ offs)
{
    __shared__ float red[7][JOFF_][64];

    const int bid  = blockIdx.x;             // 512 blocks
    const int nbid = ((bid & 7) << 6) + (bid >> 3);   // XCD chunking
    const int b    = nbid >> 6;
    const int row  = nbid & 63;

    const int t  = threadIdx.x;
    const int s  = t & 63;
    const int wv = t >> 6;
    const int wvu = __builtin_amdgcn_readfirstlane(wv);

    float m[K2_]; int idx[K2_];
#pragma unroll
    for (int ky = 0; ky < 3; ++ky) {
#pragma unroll
        for (int kx = 0; kx < 3; ++kx) {
            int y  = row - 1 + ky;
            int xx = s  - 1 + kx;
            bool v = (y >= 0) & (y < H_) & (xx >= 0) & (xx < W_);
            int yc = min(max(y, 0), H_ - 1);
            int xc = min(max(xx, 0), W_ - 1);
            m[ky*3+kx]   = v ? 1.0f : 0.0f;
            idx[ky*3+kx] = yc * W_ + xc;
        }
    }

    const float* xb = x + ((size_t)b << 19) + ((size_t)wvu << 16);
    const float* wb = w_off + wvu * 16 * K2_;

    float acc[JOFF_];
#pragma unroll
    for (int j = 0; j < JOFF_; ++j) acc[j] = 0.f;

    for (int c = 0; c < 16; ++c) {
        const float* xc = xb + (c << 12);
        float xv[K2_];
#pragma unroll
        for (int k = 0; k < K2_; ++k) xv[k] = xc[idx[k]] * m[k];
#pragma unroll
        for (int k = 0; k < K2_; ++k) {
            const float* wp = wb + c * K2_ + k;
#pragma unroll
            for (int j = 0; j < JOFF_; ++j)
                acc[j] = fmaf(wp[(size_t)j * CK_], xv[k], acc[j]);
        }
    }

    if (wv > 0) {
#pragma unroll
        for (int j = 0; j < JOFF_; ++j) red[wv-1][j][s] = acc[j];
    }
    __syncthreads();
    if (wv == 0) {
#pragma unroll
        for (int j = 0; j < JOFF_; ++j) {
            float r = acc[j];
#pragma unroll
            for (int w = 0; w < 7; ++w) r += red[w][j][s];
            r += b_off[j];
            offs[((size_t)(b * JOFF_ + j) << 12) + (row << 6) + s] = r;
        }
    }
}

// ---------------------------------------------------------------------------
// Kernel X: x NCHW f32 -> xt NHWC bf16 ([b][hw][c], c fastest).
// Tiled transpose via LDS; coalesced reads and 16B coalesced writes.
// ---------------------------------------------------------------------------
__global__ __launch_bounds__(512) void nhwc_kernel(
    const float* __restrict__ x, ushort* __restrict__ xt)
{
    __shared__ float tile[64][65];
    const int blk = blockIdx.x;            // 8 b * 2 ct * 64 ht = 1024
    const int ht = blk & 63;
    const int ct = (blk >> 6) & 1;
    const int b  = blk >> 7;
    const int t  = threadIdx.x;
    const int tx = t & 63, ty = t >> 6;    // ty 0..7

    const float* xs = x + ((size_t)(b * C_ + ct * 64) << 12) + (ht << 6);
#pragma unroll
    for (int i = 0; i < 8; ++i) {
        int c = i * 8 + ty;
        tile[c][tx] = xs[((size_t)c << 12) + tx];
    }
    __syncthreads();

    const int r  = t >> 3;                 // position 0..63
    const int co = (t & 7) * 8;            // channel octet
    short8 pack;
#pragma unroll
    for (int j = 0; j < 8; ++j) pack[j] = (short)f2bf(tile[co + j][r]);
    *reinterpret_cast<short8*>(
        xt + ((((size_t)b << 12) + (ht << 6) + r) << 7) + ct * 64 + co) = pack;
}

// ---------------------------------------------------------------------------
// Kernel T: w_def -> wt[k][o][c] bf16 (tap-major, LINEAR).
// ---------------------------------------------------------------------------
__global__ __launch_bounds__(256) void transpose_wdef_kernel(
    const float* __restrict__ w_def, ushort* __restrict__ wt)
{
    int t = blockIdx.x * 256 + threadIdx.x;
    if (t >= K2_ * COUT_ * C_) return;
    int c = t & 127;
    int o = (t >> 7) & 127;
    int k = t >> 14;
    float v = w_def[((size_t)o * C_ + c) * K2_ + k];
    wt[((size_t)k * COUT_ + o) * C_ + c] = f2bf(v);
}

// ---------------------------------------------------------------------------
// Kernel B: fused deformable gather + MFMA GEMM, single barrier per tap.
// 512 thr = 8 waves; wave = 16-row M strip, N=64 in-wave. Per tap:
//   [issue gather(k+1) raw loads] [issue A(k+1) loads] [MFMA(k): LDS only]
//   [bilinear math + sB write (k+1)] [barrier] [aC <- aN]
// vmcnt order: gather loads oldest -> math's wait leaves A loads in flight;
// MFMA phase has NO vmcnt dependence at all.
// ---------------------------------------------------------------------------
__global__ __launch_bounds__(512, 4) void deform_mfma_kernel(
    const ushort* __restrict__ xt, const float* __restrict__ offs,
    const ushort* __restrict__ wt, float* __restrict__ out)
{
    __shared__ ushort sB[2][64][C_];         // 32 KB, XOR-swizzled
    __shared__ float  s_off[JOFF_][64];      // 4.6 KB

    const int bid  = blockIdx.x;             // 512 blocks
    const int nbid = ((bid & 7) << 6) + (bid >> 3);   // XCD chunking
    const int s0   = nbid << 6;
    const int b    = s0 >> 12;
    const int hw0  = s0 & (HW_ - 1);
    const int ho   = hw0 >> 6;

    const int t    = threadIdx.x;
    const int wid  = t >> 6, lane = t & 63;
    const int sg   = lane;                   // gather position = lane
    const int arow = lane & 15;
    const int akk  = (lane >> 4) << 3;
    const int swz  = (sg & 7) << 3;
    const ushort* xtb = xt + ((size_t)b << 19);   // b * 4096 * 128

    for (int e = t; e < JOFF_ * 64; e += 512) {
        int j = e >> 6, s = e & 63;
        s_off[j][s] = offs[((size_t)(b * JOFF_ + j) << 12) + hw0 + s];
    }
    __syncthreads();

    f32x4  acc[4] = {};
    short8 aC[4], aN[4];
    short8 g[8];
    float  ca00, ca01, ca10, ca11;

    auto load_a = [&](int k, short8* dst) {
        const ushort* wk = wt + (size_t)k * (COUT_ * C_)
                         + (wid * 16 + arow) * C_ + akk;
#pragma unroll
        for (int kc = 0; kc < 4; ++kc)
            dst[kc] = *reinterpret_cast<const short8*>(wk + kc * 32);
    };

    auto gather_load = [&](int k) {
        float dy = s_off[2*k    ][sg];
        float dx = s_off[2*k + 1][sg];
        float py = (float)(ho - 1 + k/3) + dy;
        float px = (float)(sg - 1 + k%3) + dx;
        float y0f = floorf(py), x0f = floorf(px);
        float wy = py - y0f,    wx = px - x0f;
        int y0 = (int)y0f, x0 = (int)x0f;
        int y1 = y0 + 1,   x1 = x0 + 1;
        float vy0 = (y0 >= 0 && y0 < H_) ? 1.f : 0.f;
        float vy1 = (y1 >= 0 && y1 < H_) ? 1.f : 0.f;
        float vx0 = (x0 >= 0 && x0 < W_) ? 1.f : 0.f;
        float vx1 = (x1 >= 0 && x1 < W_) ? 1.f : 0.f;
        int y0c = min(max(y0, 0), H_-1), y1c = min(max(y1, 0), H_-1);
        int x0c = min(max(x0, 0), W_-1), x1c = min(max(x1, 0), W_-1);
        int bx  = min(max(x0, 0), W_-2);     // column pair [bx, bx+1]
        float wx0 = (1.f - wx) * vx0, wx1 = wx * vx1;
        float ex0 = (x0c == bx ? wx0 : 0.f) + (x1c == bx ? wx1 : 0.f);
        float ex1 = (x0c == bx ? 0.f : wx0) + (x1c == bx ? 0.f : wx1);
        float r0 = (1.f - wy) * vy0, r1 = wy * vy1;
        ca00 = r0*ex0; ca01 = r0*ex1; ca10 = r1*ex0; ca11 = r1*ex1;
        const ushort* p0 = xtb + (((y0c << 6) + bx) << 7) + wid * 16;
        const ushort* p1 = xtb + (((y1c << 6) + bx) << 7) + wid * 16;
        g[0] = *reinterpret_cast<const short8*>(p0);
        g[1] = *reinterpret_cast<const short8*>(p0 + 8);
        g[2] = *reinterpret_cast<const short8*>(p0 + 128);
        g[3] = *reinterpret_cast<const short8*>(p0 + 136);
        g[4] = *reinterpret_cast<const short8*>(p1);
        g[5] = *reinterpret_cast<const short8*>(p1 + 8);
        g[6] = *reinterpret_cast<const short8*>(p1 + 136 - 8);
        g[7] = *reinterpret_cast<const short8*>(p1 + 136);
    };

    auto gather_math_store = [&](int buf) {
#pragma unroll
        for (int j = 0; j < 4; ++j) {
            float v[4];
#pragma unroll
            for (int q = 0; q < 4; ++q) {
                int i  = j*4 + q;            // channel 0..15
                int hi = i >> 3;             // octet
                int ii = i & 7;
                float t00 = bf2f((ushort)g[0 + hi][ii]);
                float t01 = bf2f((ushort)g[2 + hi][ii]);
                float t10 = bf2f((ushort)g[4 + hi][ii]);
                float t11 = bf2f((ushort)g[6 + hi][ii]);
                float vv = ca00 * t00;
                vv = fmaf(ca01, t01, vv);
                vv = fmaf(ca10, t10, vv);
                vv = fmaf(ca11, t11, vv);
                v[q] = vv;
            }
            uint2 pk;
            pk.x = (uint)f2bf(v[0]) | ((uint)f2bf(v[1]) << 16);
            pk.y = (uint)f2bf(v[2]) | ((uint)f2bf(v[3]) << 16);
            *reinterpret_cast<uint2*>(&sB[buf][sg][(wid*16 + j*4) ^ swz]) = pk;
        }
    };

    // ---- prologue
    load_a(0, aC);
    gather_load(0);
    gather_math_store(0);
    __syncthreads();

    for (int k = 0; k < K2_; ++k) {
        if (k < K2_ - 1) { gather_load(k + 1); load_a(k + 1, aN); }

        // ---- MFMA(k): LDS-only operands, no vmcnt waits
        const int buf = k & 1;
#pragma unroll
        for (int kc = 0; kc < 4; ++kc) {
#pragma unroll
            for (int ni = 0; ni < 4; ++ni) {
                int srow = ni*16 + arow;
                short8 bF = *reinterpret_cast<const short8*>(
                    &sB[buf][srow][(kc*32 + akk) ^ ((srow & 7) << 3)]);
                acc[ni] = __builtin_amdgcn_mfma_f32_16x16x32_bf16(
                    aC[kc], bF, acc[ni], 0, 0, 0);
            }
        }

        if (k < K2_ - 1) gather_math_store((k + 1) & 1);
        __syncthreads();
        if (k < K2_ - 1) {
#pragma unroll
            for (int kc = 0; kc < 4; ++kc) aC[kc] = aN[kc];
        }
    }

    // ---- epilogue: C/D layout col=lane&15, row=(lane>>4)*4+reg; nt stores
#pragma unroll
    for (int ni = 0; ni < 4; ++ni) {
#pragma unroll
        for (int r = 0; r < 4; ++r) {
            int o = wid*16 + ((lane >> 4) << 2) + r;
            int s = ni*16 + arow;
            __builtin_nontemporal_store(acc[ni][r],
                &out[(((size_t)(b*COUT_ + o)) << 12) + hw0 + s]);
        }
    }
}

// ---------------------------------------------------------------------------
extern "C" void kernel_launch(void* const* d_in, const int* in_sizes, int n_in,
                              void* d_out, int out_size, void* d_ws, size_t ws_size,
                              hipStream_t stream) {
    const float* x     = (const float*)d_in[0];
    const float* w_off = (const float*)d_in[1];
    const float* b_off = (const float*)d_in[2];
    const float* w_def = (const float*)d_in[3];
    float* out  = (float*)d_out;

    char* ws = (char*)d_ws;
    float*  offs = (float*)ws;                         // 2,359,296 B
    ushort* wt   = (ushort*)(ws + 2359296);            //   294,912 B
    ushort* xtp  = (ushort*)(ws + 2359296 + 294912);   // 8,388,608 B

    // Kernel A: offsets (one block per (b,row))
    offset_conv_kernel<<<B_ * H_, 512, 0, stream>>>(x, w_off, b_off, offs);
    // Kernel X: x -> NHWC bf16
    nhwc_kernel<<<1024, 512, 0, stream>>>(x, xtp);
    // Kernel T: w_def -> bf16 tap-major
    {
        int total  = K2_ * COUT_ * C_;
        transpose_wdef_kernel<<<(total + 255) / 256, 256, 0, stream>>>(w_def, wt);
    }
    // Kernel B: fused gather + MFMA GEMM
    deform_mfma_kernel<<<(B_ * HW_) / 64, 512, 0, stream>>>(xtp, offs, wt, out);
}

// Round 8
// 81.747 us; speedup vs baseline: 2.0738x; 1.2540x over previous
//
#include <hip/hip_runtime.h>
#include <hip/hip_bf16.h>

// Problem constants (from reference)
#define B_    8
#define C_    128
#define H_    64
#define W_    64
#define COUT_ 128
#define K2_   9
#define JOFF_ 18            // 2*K*K offset channels
#define HW_   (H_*W_)       // 4096
#define CK_   (C_*K2_)      // 1152

typedef short  short8 __attribute__((ext_vector_type(8)));   // 8 bf16 in 4 VGPR
typedef float  f32x4  __attribute__((ext_vector_type(4)));

__device__ __forceinline__ ushort f2bf(float f) {
    __hip_bfloat16 h = __float2bfloat16(f);
    return *reinterpret_cast<ushort*>(&h);
}
__device__ __forceinline__ float bf2f(ushort u) {
    return __uint_as_float(((uint)u) << 16);
}

// ---------------------------------------------------------------------------
// Kernel X: x NCHW f32 -> xt NHWC bf16 ([b][hw][c], c fastest).
// ---------------------------------------------------------------------------
__global__ __launch_bounds__(512) void nhwc_kernel(
    const float* __restrict__ x, ushort* __restrict__ xt)
{
    __shared__ float tile[64][65];
    const int blk = blockIdx.x;            // 8 b * 2 ct * 64 ht = 1024
    const int ht = blk & 63;
    const int ct = (blk >> 6) & 1;
    const int b  = blk >> 7;
    const int t  = threadIdx.x;
    const int tx = t & 63, ty = t >> 6;    // ty 0..7

    const float* xs = x + ((size_t)(b * C_ + ct * 64) << 12) + (ht << 6);
#pragma unroll
    for (int i = 0; i < 8; ++i) {
        int c = i * 8 + ty;
        tile[c][tx] = xs[((size_t)c << 12) + tx];
    }
    __syncthreads();

    const int r  = t >> 3;                 // position 0..63
    const int co = (t & 7) * 8;            // channel octet
    short8 pack;
#pragma unroll
    for (int j = 0; j < 8; ++j) pack[j] = (short)f2bf(tile[co + j][r]);
    *reinterpret_cast<short8*>(
        xt + ((((size_t)b << 12) + (ht << 6) + r) << 7) + ct * 64 + co) = pack;
}

// ---------------------------------------------------------------------------
// Kernel T: both weight transposes.
//   wt     [k][o][c]  bf16 (tap-major)            for the deform GEMM A
//   wt_off [k][j32][c] bf16 (tap-major, 32-row M pad, rows 18..31 zero)
// ---------------------------------------------------------------------------
__global__ __launch_bounds__(256) void transpose_w_kernel(
    const float* __restrict__ w_def, const float* __restrict__ w_off,
    ushort* __restrict__ wt, ushort* __restrict__ wt_off)
{
    int t = blockIdx.x * 256 + threadIdx.x;
    if (t < K2_ * COUT_ * C_) {
        int c = t & 127;
        int o = (t >> 7) & 127;
        int k = t >> 14;
        float v = w_def[((size_t)o * C_ + c) * K2_ + k];
        wt[((size_t)k * COUT_ + o) * C_ + c] = f2bf(v);
    } else {
        int i = t - K2_ * COUT_ * C_;
        if (i < K2_ * 32 * C_) {
            int c = i & 127;
            int j = (i >> 7) & 31;
            int k = i >> 12;
            float v = (j < JOFF_) ? w_off[((size_t)j * C_ + c) * K2_ + k] : 0.f;
            wt_off[(((size_t)k * 32) + j) * C_ + c] = f2bf(v);
        }
    }
}

// ---------------------------------------------------------------------------
// Kernel B: offset conv (MFMA prologue) + fused deformable gather + MFMA GEMM.
// Block = 512 threads (8 waves), one image row: 128 out-ch x 64 positions.
// Prologue: per source row r (3 rows), stage row into zero-guarded swizzled
//   offB[66][128]; 3 taps = column-shifted B reads; 36 MFMA vs wt_off ->
//   offsets written straight to s_off LDS.
// Main loop per tap (single RAW barrier, lgkmcnt-only drain):
//   [issue gather(k+1)] [issue A(k+1)] [MFMA(k): LDS B, reg A]
//   [bilinear math + sB store (k+1)] [lgkmcnt(0); s_barrier]
// VMEM loads (all register-destined) stay in flight across the barrier.
// ---------------------------------------------------------------------------
__global__ __launch_bounds__(512, 4) void deform_mfma_kernel(
    const ushort* __restrict__ xt, const ushort* __restrict__ wt,
    const ushort* __restrict__ wt_off, const float* __restrict__ b_off,
    float* __restrict__ out)
{
    __shared__ ushort sB[2][64][C_];         // 32 KB, XOR-swizzled
    __shared__ ushort offB[66][C_];          // 16.9 KB, zero guard rows 0/65
    __shared__ float  s_off[JOFF_][64];      // 4.6 KB offsets for this row

    const int bid  = blockIdx.x;             // 512 blocks
    const int nbid = ((bid & 7) << 6) + (bid >> 3);   // XCD chunking
    const int s0   = nbid << 6;
    const int b    = s0 >> 12;
    const int hw0  = s0 & (HW_ - 1);
    const int ho   = hw0 >> 6;

    const int t    = threadIdx.x;
    const int wid  = t >> 6, lane = t & 63;
    const int sg   = lane;                   // gather position = lane
    const int arow = lane & 15;
    const int akk  = (lane >> 4) << 3;
    const int swz  = (sg & 7) << 3;
    const ushort* xtb = xt + ((size_t)b << 19);   // b * 4096 * 128

    // ================= offset-conv MFMA prologue =================
    if (t < 128) {                           // zero guard rows (cols -1, 64)
        int rr = (t >> 6) ? 65 : 0;
        reinterpret_cast<uint*>(&offB[rr][0])[t & 63] = 0u;
    }

    f32x4 oacc = {};
    const int wmO = wid >> 2, wnO = wid & 3; // M=32 (2x16), N=64 (4x16)
    for (int r = 0; r < 3; ++r) {
        int yr = ho - 1 + r;
        bool inb = (yr >= 0) && (yr < H_);
        // stage source row yr into offB[1..64] (swizzled); zeros if OOB
#pragma unroll
        for (int i = 0; i < 2; ++i) {
            int idx  = t * 2 + i;            // 0..1023
            int srow = idx >> 4;             // source position 0..63
            int grp  = idx & 15;             // 16B chunk of 128-ch row
            short8 val = {};
            if (inb)
                val = *reinterpret_cast<const short8*>(
                    xtb + (((size_t)(yr << 6) + srow) << 7) + grp * 8);
            int drow = srow + 1;
            *reinterpret_cast<short8*>(
                &offB[drow][(grp * 8) ^ ((drow & 7) << 3)]) = val;
        }
        __syncthreads();
#pragma unroll
        for (int kx = 0; kx < 3; ++kx) {
            int k = r * 3 + kx;
            const ushort* wo = wt_off
                + (((size_t)k * 32) + wmO * 16 + arow) * C_ + akk;
            int srowB = wnO * 16 + arow + kx;        // buf row = s + kx
            int key   = (srowB & 7) << 3;
#pragma unroll
            for (int kc = 0; kc < 4; ++kc) {
                short8 aO = *reinterpret_cast<const short8*>(wo + kc * 32);
                short8 bO = *reinterpret_cast<const short8*>(
                    &offB[srowB][(kc * 32 + akk) ^ key]);
                oacc = __builtin_amdgcn_mfma_f32_16x16x32_bf16(aO, bO, oacc, 0, 0, 0);
            }
        }
        __syncthreads();
    }
    {   // C/D layout: row j = wmO*16 + (lane>>4)*4 + r, col s = wnO*16 + arow
        int sO = wnO * 16 + arow;
#pragma unroll
        for (int r4 = 0; r4 < 4; ++r4) {
            int j = wmO * 16 + ((lane >> 4) << 2) + r4;
            if (j < JOFF_) s_off[j][sO] = oacc[r4] + b_off[j];
        }
    }
    __syncthreads();

    // ================= fused gather + MFMA main loop =================
    f32x4  acc[4] = {};
    short8 aC[4], aN[4];
    short8 g[8];
    float  ca00, ca01, ca10, ca11;

    auto load_a = [&](int k, short8* dst) {
        const ushort* wk = wt + (size_t)k * (COUT_ * C_)
                         + (wid * 16 + arow) * C_ + akk;
#pragma unroll
        for (int kc = 0; kc < 4; ++kc)
            dst[kc] = *reinterpret_cast<const short8*>(wk + kc * 32);
    };

    auto gather_load = [&](int k) {
        float dy = s_off[2*k    ][sg];
        float dx = s_off[2*k + 1][sg];
        float py = (float)(ho - 1 + k/3) + dy;
        float px = (float)(sg - 1 + k%3) + dx;
        float y0f = floorf(py), x0f = floorf(px);
        float wy = py - y0f,    wx = px - x0f;
        int y0 = (int)y0f, x0 = (int)x0f;
        int y1 = y0 + 1,   x1 = x0 + 1;
        float vy0 = (y0 >= 0 && y0 < H_) ? 1.f : 0.f;
        float vy1 = (y1 >= 0 && y1 < H_) ? 1.f : 0.f;
        float vx0 = (x0 >= 0 && x0 < W_) ? 1.f : 0.f;
        float vx1 = (x1 >= 0 && x1 < W_) ? 1.f : 0.f;
        int y0c = min(max(y0, 0), H_-1), y1c = min(max(y1, 0), H_-1);
        int x0c = min(max(x0, 0), W_-1), x1c = min(max(x1, 0), W_-1);
        int bx  = min(max(x0, 0), W_-2);     // column pair [bx, bx+1]
        float wx0 = (1.f - wx) * vx0, wx1 = wx * vx1;
        float ex0 = (x0c == bx ? wx0 : 0.f) + (x1c == bx ? wx1 : 0.f);
        float ex1 = (x0c == bx ? 0.f : wx0) + (x1c == bx ? 0.f : wx1);
        float r0 = (1.f - wy) * vy0, r1 = wy * vy1;
        ca00 = r0*ex0; ca01 = r0*ex1; ca10 = r1*ex0; ca11 = r1*ex1;
        const ushort* p0 = xtb + (((y0c << 6) + bx) << 7) + wid * 16;
        const ushort* p1 = xtb + (((y1c << 6) + bx) << 7) + wid * 16;
        g[0] = *reinterpret_cast<const short8*>(p0);
        g[1] = *reinterpret_cast<const short8*>(p0 + 8);
        g[2] = *reinterpret_cast<const short8*>(p0 + 128);
        g[3] = *reinterpret_cast<const short8*>(p0 + 136);
        g[4] = *reinterpret_cast<const short8*>(p1);
        g[5] = *reinterpret_cast<const short8*>(p1 + 8);
        g[6] = *reinterpret_cast<const short8*>(p1 + 128);
        g[7] = *reinterpret_cast<const short8*>(p1 + 136);
    };

    auto gather_math_store = [&](int buf) {
#pragma unroll
        for (int j = 0; j < 4; ++j) {
            float v[4];
#pragma unroll
            for (int q = 0; q < 4; ++q) {
                int i  = j*4 + q;            // channel 0..15
                int hi = i >> 3;
                int ii = i & 7;
                float t00 = bf2f((ushort)g[0 + hi][ii]);
                float t01 = bf2f((ushort)g[2 + hi][ii]);
                float t10 = bf2f((ushort)g[4 + hi][ii]);
                float t11 = bf2f((ushort)g[6 + hi][ii]);
                float vv = ca00 * t00;
                vv = fmaf(ca01, t01, vv);
                vv = fmaf(ca10, t10, vv);
                vv = fmaf(ca11, t11, vv);
                v[q] = vv;
            }
            uint2 pk;
            pk.x = (uint)f2bf(v[0]) | ((uint)f2bf(v[1]) << 16);
            pk.y = (uint)f2bf(v[2]) | ((uint)f2bf(v[3]) << 16);
            *reinterpret_cast<uint2*>(&sB[buf][sg][(wid*16 + j*4) ^ swz]) = pk;
        }
    };

    // ---- prologue
    load_a(0, aC);
    gather_load(0);
    gather_math_store(0);
    __syncthreads();

    for (int k = 0; k < K2_; ++k) {
        if (k < K2_ - 1) { gather_load(k + 1); load_a(k + 1, aN); }

        // ---- MFMA(k): LDS B, register A
        const int buf = k & 1;
#pragma unroll
        for (int kc = 0; kc < 4; ++kc) {
#pragma unroll
            for (int ni = 0; ni < 4; ++ni) {
                int srow = ni*16 + arow;
                short8 bF = *reinterpret_cast<const short8*>(
                    &sB[buf][srow][(kc*32 + akk) ^ ((srow & 7) << 3)]);
                acc[ni] = __builtin_amdgcn_mfma_f32_16x16x32_bf16(
                    aC[kc], bF, acc[ni], 0, 0, 0);
            }
        }

        if (k < K2_ - 1) gather_math_store((k + 1) & 1);

        // RAW barrier: drain LDS ops only; VMEM prefetches stay in flight
        asm volatile("s_waitcnt lgkmcnt(0)" ::: "memory");
        __builtin_amdgcn_s_barrier();

        if (k < K2_ - 1) {
#pragma unroll
            for (int kc = 0; kc < 4; ++kc) aC[kc] = aN[kc];
        }
    }

    // ---- epilogue: C/D layout col=lane&15, row=(lane>>4)*4+reg; nt stores
#pragma unroll
    for (int ni = 0; ni < 4; ++ni) {
#pragma unroll
        for (int r = 0; r < 4; ++r) {
            int o = wid*16 + ((lane >> 4) << 2) + r;
            int s = ni*16 + arow;
            __builtin_nontemporal_store(acc[ni][r],
                &out[(((size_t)(b*COUT_ + o)) << 12) + hw0 + s]);
        }
    }
}

// ---------------------------------------------------------------------------
extern "C" void kernel_launch(void* const* d_in, const int* in_sizes, int n_in,
                              void* d_out, int out_size, void* d_ws, size_t ws_size,
                              hipStream_t stream) {
    const float* x     = (const float*)d_in[0];
    const float* w_off = (const float*)d_in[1];
    const float* b_off = (const float*)d_in[2];
    const float* w_def = (const float*)d_in[3];
    float* out  = (float*)d_out;

    char* ws = (char*)d_ws;
    ushort* xtp    = (ushort*)ws;                         // 8,388,608 B
    ushort* wt     = (ushort*)(ws + 8388608);             //   294,912 B
    ushort* wt_off = (ushort*)(ws + 8388608 + 294912);    //    73,728 B

    // Kernel X: x -> NHWC bf16
    nhwc_kernel<<<1024, 512, 0, stream>>>(x, xtp);
    // Kernel T: both weight transposes
    {
        int total  = K2_ * COUT_ * C_ + K2_ * 32 * C_;    // 184,320
        transpose_w_kernel<<<(total + 255) / 256, 256, 0, stream>>>(
            w_def, w_off, wt, wt_off);
    }
    // Kernel B: fused offsets + gather + MFMA GEMM
    deform_mfma_kernel<<<(B_ * HW_) / 64, 512, 0, stream>>>(
        xtp, wt, wt_off, b_off, out);
}

// Round 9
// 80.819 us; speedup vs baseline: 2.0976x; 1.0115x over previous
//
#include <hip/hip_runtime.h>
#include <hip/hip_bf16.h>

// Problem constants (from reference)
#define B_    8
#define C_    128
#define H_    64
#define W_    64
#define COUT_ 128
#define K2_   9
#define JOFF_ 18            // 2*K*K offset channels
#define HW_   (H_*W_)       // 4096
#define CK_   (C_*K2_)      // 1152

typedef short  short8 __attribute__((ext_vector_type(8)));   // 8 bf16 in 4 VGPR
typedef float  f32x4  __attribute__((ext_vector_type(4)));

__device__ __forceinline__ ushort f2bf(float f) {
    __hip_bfloat16 h = __float2bfloat16(f);
    return *reinterpret_cast<ushort*>(&h);
}
__device__ __forceinline__ float bf2f(ushort u) {
    return __uint_as_float(((uint)u) << 16);
}

// ---------------------------------------------------------------------------
// Kernel X: x NCHW f32 -> xt NHWC bf16 ([b][hw][c], c fastest).
// ---------------------------------------------------------------------------
__global__ __launch_bounds__(512) void nhwc_kernel(
    const float* __restrict__ x, ushort* __restrict__ xt)
{
    __shared__ float tile[64][65];
    const int blk = blockIdx.x;            // 8 b * 2 ct * 64 ht = 1024
    const int ht = blk & 63;
    const int ct = (blk >> 6) & 1;
    const int b  = blk >> 7;
    const int t  = threadIdx.x;
    const int tx = t & 63, ty = t >> 6;    // ty 0..7

    const float* xs = x + ((size_t)(b * C_ + ct * 64) << 12) + (ht << 6);
#pragma unroll
    for (int i = 0; i < 8; ++i) {
        int c = i * 8 + ty;
        tile[c][tx] = xs[((size_t)c << 12) + tx];
    }
    __syncthreads();

    const int r  = t >> 3;                 // position 0..63
    const int co = (t & 7) * 8;            // channel octet
    short8 pack;
#pragma unroll
    for (int j = 0; j < 8; ++j) pack[j] = (short)f2bf(tile[co + j][r]);
    *reinterpret_cast<short8*>(
        xt + ((((size_t)b << 12) + (ht << 6) + r) << 7) + ct * 64 + co) = pack;
}

// ---------------------------------------------------------------------------
// Kernel T: both weight transposes.
//   wt     [k][o][c]  bf16 (tap-major)            for the deform GEMM A
//   wt_off [k][j32][c] bf16 (tap-major, 32-row M pad, rows 18..31 zero)
// ---------------------------------------------------------------------------
__global__ __launch_bounds__(256) void transpose_w_kernel(
    const float* __restrict__ w_def, const float* __restrict__ w_off,
    ushort* __restrict__ wt, ushort* __restrict__ wt_off)
{
    int t = blockIdx.x * 256 + threadIdx.x;
    if (t < K2_ * COUT_ * C_) {
        int c = t & 127;
        int o = (t >> 7) & 127;
        int k = t >> 14;
        float v = w_def[((size_t)o * C_ + c) * K2_ + k];
        wt[((size_t)k * COUT_ + o) * C_ + c] = f2bf(v);
    } else {
        int i = t - K2_ * COUT_ * C_;
        if (i < K2_ * 32 * C_) {
            int c = i & 127;
            int j = (i >> 7) & 31;
            int k = i >> 12;
            float v = (j < JOFF_) ? w_off[((size_t)j * C_ + c) * K2_ + k] : 0.f;
            wt_off[(((size_t)k * 32) + j) * C_ + c] = f2bf(v);
        }
    }
}

// ---------------------------------------------------------------------------
// Kernel B: offset conv (MFMA prologue) + fused deformable gather + MFMA GEMM.
// Block = 512 threads (8 waves), one image row: 128 out-ch x 64 positions.
// LDS budget 37,376 B (sB doubles as the prologue's offB staging buffer) ->
// 4 blocks/CU, 32 waves. XOR swizzle key = (row&15)<<3 on all sB/offB
// accesses (write & read identically): 64 write lanes spread over 16 column
// octets -> 4-way max write conflict; b128 reads stay contiguous.
// Main loop per tap (single RAW barrier, lgkmcnt-only drain):
//   [issue gather(k+1)] [issue A(k+1)] [MFMA(k): LDS B, reg A]
//   [bilinear math + sB store (k+1)] [lgkmcnt(0); s_barrier]
// ---------------------------------------------------------------------------
__global__ __launch_bounds__(512, 4) void deform_mfma_kernel(
    const ushort* __restrict__ xt, const ushort* __restrict__ wt,
    const ushort* __restrict__ wt_off, const float* __restrict__ b_off,
    float* __restrict__ out)
{
    __shared__ ushort sB[2][64][C_];         // 32 KB; prologue overlays offB here
    __shared__ float  s_off[JOFF_][64];      // 4.6 KB offsets for this row

    // offB[66][128] overlays sB (16.9 KB <= 32 KB); dead before sB first write
    ushort (*offB)[C_] = reinterpret_cast<ushort (*)[C_]>(&sB[0][0][0]);

    const int bid  = blockIdx.x;             // 512 blocks
    const int nbid = ((bid & 7) << 6) + (bid >> 3);   // XCD chunking
    const int s0   = nbid << 6;
    const int b    = s0 >> 12;
    const int hw0  = s0 & (HW_ - 1);
    const int ho   = hw0 >> 6;

    const int t    = threadIdx.x;
    const int wid  = t >> 6, lane = t & 63;
    const int sg   = lane;                   // gather position = lane
    const int arow = lane & 15;
    const int akk  = (lane >> 4) << 3;
    const int swz  = (sg & 15) << 3;
    const ushort* xtb = xt + ((size_t)b << 19);   // b * 4096 * 128

    // ================= offset-conv MFMA prologue =================
    if (t < 128) {                           // zero guard rows (cols -1, 64)
        int rr = (t >> 6) ? 65 : 0;
        reinterpret_cast<uint*>(&offB[rr][0])[t & 63] = 0u;
    }

    f32x4 oacc = {};
    const int wmO = wid >> 2, wnO = wid & 3; // M=32 (2x16), N=64 (4x16)
    for (int r = 0; r < 3; ++r) {
        int yr = ho - 1 + r;
        bool inb = (yr >= 0) && (yr < H_);
        // stage source row yr into offB[1..64] (swizzled); zeros if OOB
#pragma unroll
        for (int i = 0; i < 2; ++i) {
            int idx  = t * 2 + i;            // 0..1023
            int srow = idx >> 4;             // source position 0..63
            int grp  = idx & 15;             // 16B chunk of 128-ch row
            short8 val = {};
            if (inb)
                val = *reinterpret_cast<const short8*>(
                    xtb + (((size_t)(yr << 6) + srow) << 7) + grp * 8);
            int drow = srow + 1;
            *reinterpret_cast<short8*>(
                &offB[drow][(grp * 8) ^ ((drow & 15) << 3)]) = val;
        }
        __syncthreads();
#pragma unroll
        for (int kx = 0; kx < 3; ++kx) {
            int k = r * 3 + kx;
            const ushort* wo = wt_off
                + (((size_t)k * 32) + wmO * 16 + arow) * C_ + akk;
            int srowB = wnO * 16 + arow + kx;        // buf row = s + kx
            int key   = (srowB & 15) << 3;
#pragma unroll
            for (int kc = 0; kc < 4; ++kc) {
                short8 aO = *reinterpret_cast<const short8*>(wo + kc * 32);
                short8 bO = *reinterpret_cast<const short8*>(
                    &offB[srowB][(kc * 32 + akk) ^ key]);
                oacc = __builtin_amdgcn_mfma_f32_16x16x32_bf16(aO, bO, oacc, 0, 0, 0);
            }
        }
        __syncthreads();
    }
    {   // C/D layout: row j = wmO*16 + (lane>>4)*4 + r, col s = wnO*16 + arow
        int sO = wnO * 16 + arow;
#pragma unroll
        for (int r4 = 0; r4 < 4; ++r4) {
            int j = wmO * 16 + ((lane >> 4) << 2) + r4;
            if (j < JOFF_) s_off[j][sO] = oacc[r4] + b_off[j];
        }
    }
    __syncthreads();

    // ================= fused gather + MFMA main loop =================
    f32x4  acc[4] = {};
    short8 aC[4], aN[4];
    short8 g[8];
    float  ca00, ca01, ca10, ca11;

    auto load_a = [&](int k, short8* dst) {
        const ushort* wk = wt + (size_t)k * (COUT_ * C_)
                         + (wid * 16 + arow) * C_ + akk;
#pragma unroll
        for (int kc = 0; kc < 4; ++kc)
            dst[kc] = *reinterpret_cast<const short8*>(wk + kc * 32);
    };

    auto gather_load = [&](int k) {
        float dy = s_off[2*k    ][sg];
        float dx = s_off[2*k + 1][sg];
        float py = (float)(ho - 1 + k/3) + dy;
        float px = (float)(sg - 1 + k%3) + dx;
        float y0f = floorf(py), x0f = floorf(px);
        float wy = py - y0f,    wx = px - x0f;
        int y0 = (int)y0f, x0 = (int)x0f;
        int y1 = y0 + 1,   x1 = x0 + 1;
        float vy0 = (y0 >= 0 && y0 < H_) ? 1.f : 0.f;
        float vy1 = (y1 >= 0 && y1 < H_) ? 1.f : 0.f;
        float vx0 = (x0 >= 0 && x0 < W_) ? 1.f : 0.f;
        float vx1 = (x1 >= 0 && x1 < W_) ? 1.f : 0.f;
        int y0c = min(max(y0, 0), H_-1), y1c = min(max(y1, 0), H_-1);
        int x0c = min(max(x0, 0), W_-1), x1c = min(max(x1, 0), W_-1);
        int bx  = min(max(x0, 0), W_-2);     // column pair [bx, bx+1]
        float wx0 = (1.f - wx) * vx0, wx1 = wx * vx1;
        float ex0 = (x0c == bx ? wx0 : 0.f) + (x1c == bx ? wx1 : 0.f);
        float ex1 = (x0c == bx ? 0.f : wx0) + (x1c == bx ? 0.f : wx1);
        float r0 = (1.f - wy) * vy0, r1 = wy * vy1;
        ca00 = r0*ex0; ca01 = r0*ex1; ca10 = r1*ex0; ca11 = r1*ex1;
        const ushort* p0 = xtb + (((y0c << 6) + bx) << 7) + wid * 16;
        const ushort* p1 = xtb + (((y1c << 6) + bx) << 7) + wid * 16;
        g[0] = *reinterpret_cast<const short8*>(p0);
        g[1] = *reinterpret_cast<const short8*>(p0 + 8);
        g[2] = *reinterpret_cast<const short8*>(p0 + 128);
        g[3] = *reinterpret_cast<const short8*>(p0 + 136);
        g[4] = *reinterpret_cast<const short8*>(p1);
        g[5] = *reinterpret_cast<const short8*>(p1 + 8);
        g[6] = *reinterpret_cast<const short8*>(p1 + 128);
        g[7] = *reinterpret_cast<const short8*>(p1 + 136);
    };

    auto gather_math_store = [&](int buf) {
#pragma unroll
        for (int j = 0; j < 4; ++j) {
            float v[4];
#pragma unroll
            for (int q = 0; q < 4; ++q) {
                int i  = j*4 + q;            // channel 0..15
                int hi = i >> 3;
                int ii = i & 7;
                float t00 = bf2f((ushort)g[0 + hi][ii]);
                float t01 = bf2f((ushort)g[2 + hi][ii]);
                float t10 = bf2f((ushort)g[4 + hi][ii]);
                float t11 = bf2f((ushort)g[6 + hi][ii]);
                float vv = ca00 * t00;
                vv = fmaf(ca01, t01, vv);
                vv = fmaf(ca10, t10, vv);
                vv = fmaf(ca11, t11, vv);
                v[q] = vv;
            }
            uint2 pk;
            pk.x = (uint)f2bf(v[0]) | ((uint)f2bf(v[1]) << 16);
            pk.y = (uint)f2bf(v[2]) | ((uint)f2bf(v[3]) << 16);
            *reinterpret_cast<uint2*>(&sB[buf][sg][(wid*16 + j*4) ^ swz]) = pk;
        }
    };

    // ---- prologue
    load_a(0, aC);
    gather_load(0);
    gather_math_store(0);
    __syncthreads();

    for (int k = 0; k < K2_; ++k) {
        if (k < K2_ - 1) { gather_load(k + 1); load_a(k + 1, aN); }

        // ---- MFMA(k): LDS B, register A
        const int buf = k & 1;
#pragma unroll
        for (int kc = 0; kc < 4; ++kc) {
#pragma unroll
            for (int ni = 0; ni < 4; ++ni) {
                int srow = ni*16 + arow;
                short8 bF = *reinterpret_cast<const short8*>(
                    &sB[buf][srow][(kc*32 + akk) ^ ((srow & 15) << 3)]);
                acc[ni] = __builtin_amdgcn_mfma_f32_16x16x32_bf16(
                    aC[kc], bF, acc[ni], 0, 0, 0);
            }
        }

        if (k < K2_ - 1) gather_math_store((k + 1) & 1);

        // RAW barrier: drain LDS ops only; VMEM prefetches stay in flight
        asm volatile("s_waitcnt lgkmcnt(0)" ::: "memory");
        __builtin_amdgcn_s_barrier();

        if (k < K2_ - 1) {
#pragma unroll
            for (int kc = 0; kc < 4; ++kc) aC[kc] = aN[kc];
        }
    }

    // ---- epilogue: C/D layout col=lane&15, row=(lane>>4)*4+reg; nt stores
#pragma unroll
    for (int ni = 0; ni < 4; ++ni) {
#pragma unroll
        for (int r = 0; r < 4; ++r) {
            int o = wid*16 + ((lane >> 4) << 2) + r;
            int s = ni*16 + arow;
            __builtin_nontemporal_store(acc[ni][r],
                &out[(((size_t)(b*COUT_ + o)) << 12) + hw0 + s]);
        }
    }
}

// ---------------------------------------------------------------------------
extern "C" void kernel_launch(void* const* d_in, const int* in_sizes, int n_in,
                              void* d_out, int out_size, void* d_ws, size_t ws_size,
                              hipStream_t stream) {
    const float* x     = (const float*)d_in[0];
    const float* w_off = (const float*)d_in[1];
    const float* b_off = (const float*)d_in[2];
    const float* w_def = (const float*)d_in[3];
    float* out  = (float*)d_out;

    char* ws = (char*)d_ws;
    ushort* xtp    = (ushort*)ws;                         // 8,388,608 B
    ushort* wt     = (ushort*)(ws + 8388608);             //   294,912 B
    ushort* wt_off = (ushort*)(ws + 8388608 + 294912);    //    73,728 B

    // Kernel X: x -> NHWC bf16
    nhwc_kernel<<<1024, 512, 0, stream>>>(x, xtp);
    // Kernel T: both weight transposes
    {
        int total  = K2_ * COUT_ * C_ + K2_ * 32 * C_;    // 184,320
        transpose_w_kernel<<<(total + 255) / 256, 256, 0, stream>>>(
            w_def, w_off, wt, wt_off);
    }
    // Kernel B: fused offsets + gather + MFMA GEMM
    deform_mfma_kernel<<<(B_ * HW_) / 64, 512, 0, stream>>>(
        xtp, wt, wt_off, b_off, out);
}